// Round 2
// baseline (1082.295 us; speedup 1.0000x reference)
//
#include <hip/hip_runtime.h>
#include <hip/hip_bf16.h>

namespace {

constexpr int kB = 8192;   // batch
constexpr int kH = 1024;   // hidden
constexpr int kK = 2048;   // H + I
constexpr int kG = 4 * kH; // 4096 gate cols

typedef float f32x4 __attribute__((ext_vector_type(4)));
typedef unsigned short u16x8 __attribute__((ext_vector_type(8)));

__device__ __forceinline__ unsigned short f2bf(float f) {
  return __builtin_bit_cast(unsigned short, __float2bfloat16(f));
}
__device__ __forceinline__ float sigmoidf_(float x) {
  return 1.0f / (1.0f + __expf(-x));
}
__device__ __forceinline__ u16x8 pack8(const float4 v0, const float4 v1) {
  return u16x8{f2bf(v0.x), f2bf(v0.y), f2bf(v0.z), f2bf(v0.w),
               f2bf(v1.x), f2bf(v1.y), f2bf(v1.z), f2bf(v1.w)};
}

// ---------------- Pass 1: convert/pack f32 -> bf16 into d_ws ----------------
// Aw[8192][2048] = [old_h | input] bf16
// Ww[4096][2048]: row j = h*4 + g  <- weights row g*1024 + h  (gate interleave)
// bias_i[4096]:   j = h*4 + g      <- bias[g*1024 + h]
__global__ __launch_bounds__(256) void prep_pack(
    const float* __restrict__ input, const float* __restrict__ weights,
    const float* __restrict__ bias, const float* __restrict__ old_h,
    unsigned short* __restrict__ Aw, unsigned short* __restrict__ Ww,
    float* __restrict__ bias_i) {
  const long nA = (long)kB * kK / 8;   // 2,097,152
  const long nW = (long)kG * kK / 8;   // 1,048,576
  const long t = (long)blockIdx.x * 256 + threadIdx.x;
  if (t < nA) {
    const long e = t * 8;
    const long row = e >> 11;
    const int col = (int)(e & 2047);
    const float* src = (col < kH) ? (old_h + row * kH + col)
                                  : (input + row * kH + (col - kH));
    const float4* s4 = (const float4*)src;
    *(u16x8*)(Aw + e) = pack8(s4[0], s4[1]);
  } else if (t < nA + nW) {
    const long e = (t - nA) * 8;
    const int j = (int)(e >> 11);
    const int col = (int)(e & 2047);
    const int g = j & 3, h = j >> 2;
    const float4* s4 = (const float4*)(weights + ((long)g * kH + h) * kK + col);
    *(u16x8*)(Ww + e) = pack8(s4[0], s4[1]);
  } else {
    const long r = t - nA - nW;
    if (r < kG / 8) {
      const int e = (int)(r * 8);
      #pragma unroll
      for (int q = 0; q < 8; ++q) {
        const int j = e + q;
        bias_i[j] = bias[(j & 3) * kH + (j >> 2)];
      }
    }
  }
}

// ---------------- Pass 2: bf16 MFMA GEMM + fused epilogue ----------------
// Block: 128 batch rows x 128 gate cols (= 32 hidden x 4 interleaved gates).
// 4 waves (2x2), each 64x64 = 4x4 frags of 16x16x32. BK=64, single-buffer LDS,
// global_load_lds width-16 staging (m97 structure).
__global__ __launch_bounds__(256, 2) void sublstm_gemm(
    const unsigned short* __restrict__ Aw, const unsigned short* __restrict__ Ww,
    const float* __restrict__ bias_i, const float* __restrict__ old_cell,
    float* __restrict__ out) {

  __shared__ union SM {
    struct { unsigned short A[128 * 64]; unsigned short B[128 * 64]; } t;  // 32 KB
    float Gc[32][132];                                                      // epilogue
  } sm;
  __shared__ float bias_s[128];

  const int tid  = threadIdx.x;
  const int lane = tid & 63;
  const int wid  = tid >> 6;
  const int wr   = wid >> 1;
  const int wc   = wid & 1;

  // XCD-aware swizzle: nwg=2048, 2048/8=256 per XCD; consecutive chunk shares W panel
  const int bid = blockIdx.x;
  const int swz = (bid & 7) * 256 + (bid >> 3);
  const int bm  = swz & 63;   // batch block
  const int hb  = swz >> 6;   // 128-gate-col block (32 hidden units)

  if (tid < 128) bias_s[tid] = bias_i[hb * 128 + tid];

  // staging map: LDS element e = i*2048 + wid*512 + lane*8 -> row = i*32+wid*8+lane/8, col=(lane&7)*8
  const int srow = wid * 8 + (lane >> 3);
  const int scol = (lane & 7) * 8;
  const unsigned short* ag = Aw + ((long)(bm * 128 + srow)) * kK + scol;
  const unsigned short* bg = Ww + ((long)(hb * 128 + srow)) * kK + scol;

  // MFMA fragment map (16x16x32 bf16)
  const int fr = lane & 15;
  const int ks = (lane >> 4) << 3;

  f32x4 acc[4][4];
  #pragma unroll
  for (int m = 0; m < 4; ++m)
    #pragma unroll
    for (int n = 0; n < 4; ++n)
      acc[m][n] = f32x4{0.f, 0.f, 0.f, 0.f};

  for (int kt = 0; kt < kK / 64; ++kt) {
    __syncthreads();  // previous tile fully consumed
    const int kc = kt * 64;
    #pragma unroll
    for (int i = 0; i < 4; ++i) {
      __builtin_amdgcn_global_load_lds(
          (const __attribute__((address_space(1))) unsigned int*)(ag + (long)i * (32 * kK) + kc),
          (__attribute__((address_space(3))) unsigned int*)(&sm.t.A[i * 2048 + wid * 512]),
          16, 0, 0);
      __builtin_amdgcn_global_load_lds(
          (const __attribute__((address_space(1))) unsigned int*)(bg + (long)i * (32 * kK) + kc),
          (__attribute__((address_space(3))) unsigned int*)(&sm.t.B[i * 2048 + wid * 512]),
          16, 0, 0);
    }
    __syncthreads();  // compiler drains vmcnt(0) before s_barrier

    #pragma unroll
    for (int kk = 0; kk < 2; ++kk) {
      u16x8 af[4], bfv[4];
      #pragma unroll
      for (int m = 0; m < 4; ++m)
        af[m] = *(const u16x8*)&sm.t.A[(wr * 64 + m * 16 + fr) * 64 + kk * 32 + ks];
      #pragma unroll
      for (int n = 0; n < 4; ++n)
        bfv[n] = *(const u16x8*)&sm.t.B[(wc * 64 + n * 16 + fr) * 64 + kk * 32 + ks];
      #pragma unroll
      for (int m = 0; m < 4; ++m)
        #pragma unroll
        for (int n = 0; n < 4; ++n)
          asm("v_mfma_f32_16x16x32_bf16 %0, %1, %2, %0"
              : "+v"(acc[m][n]) : "v"(af[m]), "v"(bfv[n]));
    }
  }

  // ---- fused epilogue: 4 row-chunks of 32 rows x 128 gate cols ----
  float* out_h = out;
  float* out_c = out + (long)kB * kH;

  #pragma unroll
  for (int m = 0; m < 4; ++m) {
    __syncthreads();  // MFMA ds_reads / previous chunk done (union alias safe)
    #pragma unroll
    for (int n = 0; n < 4; ++n) {
      const int col = wc * 64 + n * 16 + fr;  // C/D: col = lane&15
      #pragma unroll
      for (int j = 0; j < 4; ++j)
        sm.Gc[wr * 16 + (lane >> 4) * 4 + j][col] = acc[m][n][j];  // row=(lane>>4)*4+j
    }
    __syncthreads();

    #pragma unroll
    for (int q = 0; q < 4; ++q) {
      const int idx = tid + (q << 8);
      const int r = idx >> 5;   // chunk row 0..31
      const int h = idx & 31;   // local hidden 0..31
      const float4 gv = *(const float4*)&sm.Gc[r][h * 4];  // i,o,z,f interleaved
      const float4 bv = *(const float4*)&bias_s[h * 4];
      const float gi = sigmoidf_(gv.x + bv.x);
      const float go = sigmoidf_(gv.y + bv.y);
      const float gz = sigmoidf_(gv.z + bv.z);
      const float gf = sigmoidf_(gv.w + bv.w);
      const int grow = bm * 128 + (r >> 4) * 64 + m * 16 + (r & 15);
      const long off = (long)grow * kH + hb * 32 + h;
      const float oc = old_cell[off];
      const float nc = oc * gf + gz - gi;
      out_h[off] = sigmoidf_(nc) - go;
      out_c[off] = nc;
    }
  }
}

// ---------------- Fallback (round-1 fused kernel) if ws too small ----------------
constexpr int FBM = 128, FBH = 32, FBN = 128, FBK = 32, FNKT = kK / FBK;

__global__ __launch_bounds__(256, 2) void sublstm_fused(
    const float* __restrict__ input, const float* __restrict__ weights,
    const float* __restrict__ bias, const float* __restrict__ old_h,
    const float* __restrict__ old_cell, float* __restrict__ out) {
  __shared__ unsigned short As[FBM][FBK + 8];
  __shared__ unsigned short Bs[FBN][FBK + 8];
  __shared__ float Gc[32][FBN + 4];

  const int tid = threadIdx.x, lane = tid & 63, wid = tid >> 6;
  const int wr = wid >> 1, wc = wid & 1;
  const int bid = blockIdx.x;
  const int bm = bid & 63, hh0 = (bid >> 6) * FBH;

  const int ra = tid >> 1, ca = (tid & 1) << 4;
  const long arow = (long)bm * FBM + ra;
  const int wrow = (ra >> 5) * kH + hh0 + (ra & 31);
  const float* abase_h = old_h + arow * kH + ca;
  const float* abase_x = input + arow * kH + ca - kH;
  const float* wbase = weights + (long)wrow * kK + ca;

  const int fr = lane & 15, ks = (lane >> 4) << 3;
  f32x4 acc[4][4];
  #pragma unroll
  for (int m = 0; m < 4; ++m)
    #pragma unroll
    for (int n = 0; n < 4; ++n) acc[m][n] = f32x4{0.f, 0.f, 0.f, 0.f};

  float4 a0, a1, a2, a3, b0, b1, b2, b3;
  {
    const float4* ap4 = (const float4*)abase_h;
    const float4* wp4 = (const float4*)wbase;
    a0 = ap4[0]; a1 = ap4[1]; a2 = ap4[2]; a3 = ap4[3];
    b0 = wp4[0]; b1 = wp4[1]; b2 = wp4[2]; b3 = wp4[3];
  }
  for (int kt = 0; kt < FNKT; ++kt) {
    u16x8 pa0 = pack8(a0, a1), pa1 = pack8(a2, a3);
    u16x8 pb0 = pack8(b0, b1), pb1 = pack8(b2, b3);
    __syncthreads();
    *(u16x8*)&As[ra][ca] = pa0; *(u16x8*)&As[ra][ca + 8] = pa1;
    *(u16x8*)&Bs[ra][ca] = pb0; *(u16x8*)&Bs[ra][ca + 8] = pb1;
    __syncthreads();
    if (kt + 1 < FNKT) {
      const int k0n = (kt + 1) * FBK;
      const float* ap = (k0n < kH) ? (abase_h + k0n) : (abase_x + k0n);
      const float4* ap4 = (const float4*)ap;
      const float4* wp4 = (const float4*)(wbase + k0n);
      a0 = ap4[0]; a1 = ap4[1]; a2 = ap4[2]; a3 = ap4[3];
      b0 = wp4[0]; b1 = wp4[1]; b2 = wp4[2]; b3 = wp4[3];
    }
    u16x8 af[4], bfv[4];
    #pragma unroll
    for (int m = 0; m < 4; ++m) af[m] = *(const u16x8*)&As[wr * 64 + m * 16 + fr][ks];
    #pragma unroll
    for (int n = 0; n < 4; ++n) bfv[n] = *(const u16x8*)&Bs[wc * 64 + n * 16 + fr][ks];
    #pragma unroll
    for (int m = 0; m < 4; ++m)
      #pragma unroll
      for (int n = 0; n < 4; ++n)
        asm("v_mfma_f32_16x16x32_bf16 %0, %1, %2, %0"
            : "+v"(acc[m][n]) : "v"(af[m]), "v"(bfv[n]));
  }
  float* out_h = out;
  float* out_c = out + (long)kB * kH;
  #pragma unroll
  for (int m = 0; m < 4; ++m) {
    __syncthreads();
    #pragma unroll
    for (int n = 0; n < 4; ++n) {
      const int col = wc * 64 + n * 16 + fr;
      #pragma unroll
      for (int j = 0; j < 4; ++j)
        Gc[wr * 16 + (lane >> 4) * 4 + j][col] = acc[m][n][j];
    }
    __syncthreads();
    #pragma unroll
    for (int q = 0; q < 4; ++q) {
      const int idx = tid + (q << 8);
      const int r = idx >> 5, h = idx & 31;
      const int hg = hh0 + h;
      const float gi = sigmoidf_(Gc[r][h] + bias[hg]);
      const float go = sigmoidf_(Gc[r][32 + h] + bias[kH + hg]);
      const float gz = sigmoidf_(Gc[r][64 + h] + bias[2 * kH + hg]);
      const float gf = sigmoidf_(Gc[r][96 + h] + bias[3 * kH + hg]);
      const int grow = bm * FBM + (r >> 4) * 64 + m * 16 + (r & 15);
      const long off = (long)grow * kH + hg;
      const float oc = old_cell[off];
      const float nc = oc * gf + gz - gi;
      out_h[off] = sigmoidf_(nc) - go;
      out_c[off] = nc;
    }
  }
}

}  // namespace

extern "C" void kernel_launch(void* const* d_in, const int* in_sizes, int n_in,
                              void* d_out, int out_size, void* d_ws, size_t ws_size,
                              hipStream_t stream) {
  const float* input    = (const float*)d_in[0];
  const float* weights  = (const float*)d_in[1];
  const float* bias     = (const float*)d_in[2];
  const float* old_h    = (const float*)d_in[3];
  const float* old_cell = (const float*)d_in[4];
  float* out = (float*)d_out;

  const size_t needA = (size_t)kB * kK * 2;      // 32 MB
  const size_t needW = (size_t)kG * kK * 2;      // 16 MB
  const size_t needBias = (size_t)kG * 4;        // 16 KB

  if (ws_size >= needA + needW + needBias) {
    unsigned short* Aw = (unsigned short*)d_ws;
    unsigned short* Ww = (unsigned short*)((char*)d_ws + needA);
    float* bias_i = (float*)((char*)d_ws + needA + needW);
    const long tasks = (long)kB * kK / 8 + (long)kG * kK / 8 + kG / 8;
    const int pgrid = (int)((tasks + 255) / 256);   // 12290
    prep_pack<<<dim3(pgrid), dim3(256), 0, stream>>>(input, weights, bias, old_h,
                                                     Aw, Ww, bias_i);
    sublstm_gemm<<<dim3(2048), dim3(256), 0, stream>>>(Aw, Ww, bias_i, old_cell, out);
  } else {
    sublstm_fused<<<dim3(2048), dim3(256), 0, stream>>>(input, weights, bias, old_h,
                                                        old_cell, out);
  }
}

// Round 3
// 422.022 us; speedup vs baseline: 2.5645x; 2.5645x over previous
//
#include <hip/hip_runtime.h>
#include <hip/hip_bf16.h>

namespace {

constexpr int kB = 8192;   // batch
constexpr int kH = 1024;   // hidden
constexpr int kK = 2048;   // H + I
constexpr int kG = 4 * kH; // 4096 gate cols

typedef float f32x4 __attribute__((ext_vector_type(4)));
typedef unsigned short u16x8 __attribute__((ext_vector_type(8)));

__device__ __forceinline__ unsigned short f2bf(float f) {
  return __builtin_bit_cast(unsigned short, __float2bfloat16(f));
}
__device__ __forceinline__ float sigmoidf_(float x) {
  return 1.0f / (1.0f + __expf(-x));
}
__device__ __forceinline__ u16x8 pack8(const float4 v0, const float4 v1) {
  return u16x8{f2bf(v0.x), f2bf(v0.y), f2bf(v0.z), f2bf(v0.w),
               f2bf(v1.x), f2bf(v1.y), f2bf(v1.z), f2bf(v1.w)};
}

// ---------------- Pass 1: convert/pack f32 -> bf16 fragment-order tiles ----------------
// A tiles: [bm(64)][kt(32)] x 16KB tile, tile layout [mb(8)][kb(2)][lane(64)][8 bf16]
//   maps (row = bm*128 + mb*16 + (lane&15), k = kt*64 + kb*32 + (lane>>4)*8 + e)
//   A row-major source = [old_h | input].
// W tiles: [hb(32)][kt(32)] x 16KB, same tile layout; gate-col j = hb*128+mb*16+(lane&15),
//   j = h*4 + g interleave -> weights row g*1024+h.
// bias_i[4096]: j = h*4+g <- bias[g*1024+h]
__global__ __launch_bounds__(256) void prep_pack(
    const float* __restrict__ input, const float* __restrict__ weights,
    const float* __restrict__ bias, const float* __restrict__ old_h,
    unsigned short* __restrict__ Aw, unsigned short* __restrict__ Ww,
    float* __restrict__ bias_i) {
  const long nA = (long)kB * kK / 8;   // 2,097,152 chunks
  const long nW = (long)kG * kK / 8;   // 1,048,576 chunks
  const long t = (long)blockIdx.x * 256 + threadIdx.x;
  if (t < nA) {
    const long c = t;
    const int le = (int)(c & 63);
    const int kb = (int)((c >> 6) & 1);
    const int mb = (int)((c >> 7) & 7);
    const int kt = (int)((c >> 10) & 31);
    const int bm = (int)(c >> 15);
    const int row = bm * 128 + mb * 16 + (le & 15);
    const int k   = kt * 64 + kb * 32 + ((le >> 4) << 3);
    const float* src = (k < kH) ? (old_h + (long)row * kH + k)
                                : (input + (long)row * kH + (k - kH));
    const float4* s4 = (const float4*)src;
    *(u16x8*)(Aw + c * 8) = pack8(s4[0], s4[1]);
  } else if (t < nA + nW) {
    const long c = t - nA;
    const int le = (int)(c & 63);
    const int kb = (int)((c >> 6) & 1);
    const int mb = (int)((c >> 7) & 7);
    const int kt = (int)((c >> 10) & 31);
    const int hb = (int)(c >> 15);
    const int j  = hb * 128 + mb * 16 + (le & 15);
    const int g = j & 3, h = j >> 2;
    const int k = kt * 64 + kb * 32 + ((le >> 4) << 3);
    const float4* s4 = (const float4*)(weights + ((long)g * kH + h) * kK + k);
    *(u16x8*)(Ww + c * 8) = pack8(s4[0], s4[1]);
  } else {
    const long r = t - nA - nW;
    if (r < kG / 8) {
      const int e = (int)(r * 8);
      #pragma unroll
      for (int q = 0; q < 8; ++q) {
        const int j = e + q;
        bias_i[j] = bias[(j & 3) * kH + (j >> 2)];
      }
    }
  }
}

// ---------------- Pass 2: bf16 MFMA GEMM + fused epilogue ----------------
// Block: 128 batch rows x 128 gate cols (32 hidden x 4 interleaved gates).
// 4 waves (2x2 of 64x64). BK=64. Single-buffer LDS, global_load_lds width-16.
// LDS tiles are in fragment order -> all ds_read_b128 are lane*16B sequential
// (zero bank conflicts).
__global__ __launch_bounds__(256, 4) void sublstm_gemm(
    const unsigned short* __restrict__ Aw, const unsigned short* __restrict__ Ww,
    const float* __restrict__ bias_i, const float* __restrict__ old_cell,
    float* __restrict__ out) {

  __shared__ union SM {
    struct { unsigned short A[8192]; unsigned short B[8192]; } t;  // 32 KB
    float Gc[32][132];                                             // epilogue overlay
  } sm;
  __shared__ float bias_s[128];

  const int tid  = threadIdx.x;
  const int lane = tid & 63;
  const int wid  = tid >> 6;
  const int wr   = wid >> 1;
  const int wc   = wid & 1;

  // XCD swizzle: 2048 wgs, 256/XCD contiguous; bm fastest -> W panel L2-resident
  const int bid = blockIdx.x;
  const int swz = (bid & 7) * 256 + (bid >> 3);
  const int bm  = swz & 63;
  const int hb  = swz >> 6;

  if (tid < 128) bias_s[tid] = bias_i[hb * 128 + tid];

  const unsigned short* atile = Aw + ((long)bm * 32) * 8192;  // + kt*8192
  const unsigned short* btile = Ww + ((long)hb * 32) * 8192;

  const int soff = tid * 8;  // staging source offset per thread (shorts)

  f32x4 acc[4][4];
  #pragma unroll
  for (int m = 0; m < 4; ++m)
    #pragma unroll
    for (int n = 0; n < 4; ++n)
      acc[m][n] = f32x4{0.f, 0.f, 0.f, 0.f};

  for (int kt = 0; kt < kK / 64; ++kt) {
    __syncthreads();  // previous tile fully consumed
    const unsigned short* asrc = atile + (long)kt * 8192 + soff;
    const unsigned short* bsrc = btile + (long)kt * 8192 + soff;
    #pragma unroll
    for (int i = 0; i < 4; ++i) {
      __builtin_amdgcn_global_load_lds(
          (const __attribute__((address_space(1))) unsigned int*)(asrc + i * 2048),
          (__attribute__((address_space(3))) unsigned int*)(&sm.t.A[i * 2048 + wid * 512]),
          16, 0, 0);
      __builtin_amdgcn_global_load_lds(
          (const __attribute__((address_space(1))) unsigned int*)(bsrc + i * 2048),
          (__attribute__((address_space(3))) unsigned int*)(&sm.t.B[i * 2048 + wid * 512]),
          16, 0, 0);
    }
    __syncthreads();  // vmcnt(0) drained before barrier by compiler

    #pragma unroll
    for (int kk = 0; kk < 2; ++kk) {
      u16x8 af[4], bfv[4];
      #pragma unroll
      for (int m = 0; m < 4; ++m)
        af[m] = *(const u16x8*)&sm.t.A[((wr * 4 + m) * 2 + kk) * 512 + lane * 8];
      #pragma unroll
      for (int n = 0; n < 4; ++n)
        bfv[n] = *(const u16x8*)&sm.t.B[((wc * 4 + n) * 2 + kk) * 512 + lane * 8];
      #pragma unroll
      for (int m = 0; m < 4; ++m)
        #pragma unroll
        for (int n = 0; n < 4; ++n)
          asm("v_mfma_f32_16x16x32_bf16 %0, %1, %2, %0"
              : "+v"(acc[m][n]) : "v"(af[m]), "v"(bfv[n]));
    }
  }

  // ---- fused epilogue: 4 row-chunks of 32 rows x 128 gate cols ----
  float* out_h = out;
  float* out_c = out + (long)kB * kH;

  #pragma unroll
  for (int m = 0; m < 4; ++m) {
    __syncthreads();  // previous chunk consumed / MFMA reads done
    #pragma unroll
    for (int n = 0; n < 4; ++n) {
      const int col = wc * 64 + n * 16 + (lane & 15);  // C/D: col = lane&15
      #pragma unroll
      for (int j = 0; j < 4; ++j)
        sm.Gc[wr * 16 + (lane >> 4) * 4 + j][col] = acc[m][n][j];  // row=(lane>>4)*4+j
    }
    __syncthreads();

    #pragma unroll
    for (int q = 0; q < 4; ++q) {
      const int idx = tid + (q << 8);
      const int r = idx >> 5;   // chunk row 0..31
      const int h = idx & 31;   // local hidden 0..31
      const float4 gv = *(const float4*)&sm.Gc[r][h * 4];  // i,o,z,f interleaved
      const float4 bv = *(const float4*)&bias_s[h * 4];
      const float gi = sigmoidf_(gv.x + bv.x);
      const float go = sigmoidf_(gv.y + bv.y);
      const float gz = sigmoidf_(gv.z + bv.z);
      const float gf = sigmoidf_(gv.w + bv.w);
      const int grow = bm * 128 + (r >> 4) * 64 + m * 16 + (r & 15);
      const long off = (long)grow * kH + hb * 32 + h;
      const float oc = old_cell[off];
      const float nc = oc * gf + gz - gi;
      out_h[off] = sigmoidf_(nc) - go;
      out_c[off] = nc;
    }
  }
}

// ---------------- Fallback (round-1 fused kernel) if ws too small ----------------
constexpr int FBM = 128, FBH = 32, FBN = 128, FBK = 32, FNKT = kK / FBK;

__global__ __launch_bounds__(256, 2) void sublstm_fused(
    const float* __restrict__ input, const float* __restrict__ weights,
    const float* __restrict__ bias, const float* __restrict__ old_h,
    const float* __restrict__ old_cell, float* __restrict__ out) {
  __shared__ unsigned short As[FBM][FBK + 8];
  __shared__ unsigned short Bs[FBN][FBK + 8];
  __shared__ float Gc[32][FBN + 4];

  const int tid = threadIdx.x, lane = tid & 63, wid = tid >> 6;
  const int wr = wid >> 1, wc = wid & 1;
  const int bid = blockIdx.x;
  const int bm = bid & 63, hh0 = (bid >> 6) * FBH;

  const int ra = tid >> 1, ca = (tid & 1) << 4;
  const long arow = (long)bm * FBM + ra;
  const int wrow = (ra >> 5) * kH + hh0 + (ra & 31);
  const float* abase_h = old_h + arow * kH + ca;
  const float* abase_x = input + arow * kH + ca - kH;
  const float* wbase = weights + (long)wrow * kK + ca;

  const int fr = lane & 15, ks = (lane >> 4) << 3;
  f32x4 acc[4][4];
  #pragma unroll
  for (int m = 0; m < 4; ++m)
    #pragma unroll
    for (int n = 0; n < 4; ++n) acc[m][n] = f32x4{0.f, 0.f, 0.f, 0.f};

  float4 a0, a1, a2, a3, b0, b1, b2, b3;
  {
    const float4* ap4 = (const float4*)abase_h;
    const float4* wp4 = (const float4*)wbase;
    a0 = ap4[0]; a1 = ap4[1]; a2 = ap4[2]; a3 = ap4[3];
    b0 = wp4[0]; b1 = wp4[1]; b2 = wp4[2]; b3 = wp4[3];
  }
  for (int kt = 0; kt < FNKT; ++kt) {
    u16x8 pa0 = pack8(a0, a1), pa1 = pack8(a2, a3);
    u16x8 pb0 = pack8(b0, b1), pb1 = pack8(b2, b3);
    __syncthreads();
    *(u16x8*)&As[ra][ca] = pa0; *(u16x8*)&As[ra][ca + 8] = pa1;
    *(u16x8*)&Bs[ra][ca] = pb0; *(u16x8*)&Bs[ra][ca + 8] = pb1;
    __syncthreads();
    if (kt + 1 < FNKT) {
      const int k0n = (kt + 1) * FBK;
      const float* ap = (k0n < kH) ? (abase_h + k0n) : (abase_x + k0n);
      const float4* ap4 = (const float4*)ap;
      const float4* wp4 = (const float4*)(wbase + k0n);
      a0 = ap4[0]; a1 = ap4[1]; a2 = ap4[2]; a3 = ap4[3];
      b0 = wp4[0]; b1 = wp4[1]; b2 = wp4[2]; b3 = wp4[3];
    }
    u16x8 af[4], bfv[4];
    #pragma unroll
    for (int m = 0; m < 4; ++m) af[m] = *(const u16x8*)&As[wr * 64 + m * 16 + fr][ks];
    #pragma unroll
    for (int n = 0; n < 4; ++n) bfv[n] = *(const u16x8*)&Bs[wc * 64 + n * 16 + fr][ks];
    #pragma unroll
    for (int m = 0; m < 4; ++m)
      #pragma unroll
      for (int n = 0; n < 4; ++n)
        asm("v_mfma_f32_16x16x32_bf16 %0, %1, %2, %0"
            : "+v"(acc[m][n]) : "v"(af[m]), "v"(bfv[n]));
  }
  float* out_h = out;
  float* out_c = out + (long)kB * kH;
  #pragma unroll
  for (int m = 0; m < 4; ++m) {
    __syncthreads();
    #pragma unroll
    for (int n = 0; n < 4; ++n) {
      const int col = wc * 64 + n * 16 + fr;
      #pragma unroll
      for (int j = 0; j < 4; ++j)
        Gc[wr * 16 + (lane >> 4) * 4 + j][col] = acc[m][n][j];
    }
    __syncthreads();
    #pragma unroll
    for (int q = 0; q < 4; ++q) {
      const int idx = tid + (q << 8);
      const int r = idx >> 5, h = idx & 31;
      const int hg = hh0 + h;
      const float gi = sigmoidf_(Gc[r][h] + bias[hg]);
      const float go = sigmoidf_(Gc[r][32 + h] + bias[kH + hg]);
      const float gz = sigmoidf_(Gc[r][64 + h] + bias[2 * kH + hg]);
      const float gf = sigmoidf_(Gc[r][96 + h] + bias[3 * kH + hg]);
      const int grow = bm * FBM + (r >> 4) * 64 + m * 16 + (r & 15);
      const long off = (long)grow * kH + hg;
      const float oc = old_cell[off];
      const float nc = oc * gf + gz - gi;
      out_h[off] = sigmoidf_(nc) - go;
      out_c[off] = nc;
    }
  }
}

}  // namespace

extern "C" void kernel_launch(void* const* d_in, const int* in_sizes, int n_in,
                              void* d_out, int out_size, void* d_ws, size_t ws_size,
                              hipStream_t stream) {
  const float* input    = (const float*)d_in[0];
  const float* weights  = (const float*)d_in[1];
  const float* bias     = (const float*)d_in[2];
  const float* old_h    = (const float*)d_in[3];
  const float* old_cell = (const float*)d_in[4];
  float* out = (float*)d_out;

  const size_t needA = (size_t)kB * kK * 2;      // 32 MB
  const size_t needW = (size_t)kG * kK * 2;      // 16 MB
  const size_t needBias = (size_t)kG * 4;        // 16 KB

  if (ws_size >= needA + needW + needBias) {
    unsigned short* Aw = (unsigned short*)d_ws;
    unsigned short* Ww = (unsigned short*)((char*)d_ws + needA);
    float* bias_i = (float*)((char*)d_ws + needA + needW);
    const long tasks = (long)kB * kK / 8 + (long)kG * kK / 8 + kG / 8;
    const int pgrid = (int)((tasks + 255) / 256);
    prep_pack<<<dim3(pgrid), dim3(256), 0, stream>>>(input, weights, bias, old_h,
                                                     Aw, Ww, bias_i);
    sublstm_gemm<<<dim3(2048), dim3(256), 0, stream>>>(Aw, Ww, bias_i, old_cell, out);
  } else {
    sublstm_fused<<<dim3(2048), dim3(256), 0, stream>>>(input, weights, bias, old_h,
                                                        old_cell, out);
  }
}

// Round 4
// 335.601 us; speedup vs baseline: 3.2249x; 1.2575x over previous
//
#include <hip/hip_runtime.h>
#include <hip/hip_bf16.h>

namespace {

constexpr int kB = 8192;   // batch
constexpr int kH = 1024;   // hidden
constexpr int kK = 2048;   // H + I
constexpr int kG = 4 * kH; // 4096 gate cols

typedef float f32x4 __attribute__((ext_vector_type(4)));
typedef unsigned short u16x8 __attribute__((ext_vector_type(8)));

__device__ __forceinline__ unsigned short f2bf(float f) {
  return __builtin_bit_cast(unsigned short, __float2bfloat16(f));
}
__device__ __forceinline__ float sigmoidf_(float x) {
  return 1.0f / (1.0f + __expf(-x));
}
__device__ __forceinline__ u16x8 pack8(const float4 v0, const float4 v1) {
  return u16x8{f2bf(v0.x), f2bf(v0.y), f2bf(v0.z), f2bf(v0.w),
               f2bf(v1.x), f2bf(v1.y), f2bf(v1.z), f2bf(v1.w)};
}

// ---------------- Pass 1: tile-blocked pack f32 -> bf16 fragment-order ----------------
// One block per 16KB dest tile. Tile layout (8192 shorts):
//   short_off = mb*1024 + kb*512 + (lh*16 + r15)*8 + e
//   maps (dest_row = mb*16 + r15, k_local = kb*32 + lh*8 + e)
// A tiles: tileid = bm*32+kt, dest_row -> batch row bm*128+row, source [old_h|input]
// W tiles: tileid = hb*32+kt, dest_row -> gate col j = hb*128+row, j = h*4+g
// bias blocks: bias_i[j] = bias[(j&3)*1024 + (j>>2)]
__global__ __launch_bounds__(256) void prep_pack(
    const float* __restrict__ input, const float* __restrict__ weights,
    const float* __restrict__ bias, const float* __restrict__ old_h,
    unsigned short* __restrict__ Aw, unsigned short* __restrict__ Ww,
    float* __restrict__ bias_i) {
  const int b = blockIdx.x;
  const int tid = threadIdx.x;

  if (b >= 3072) {  // bias interleave: 2 blocks x 256 threads x 8
    const int base = (b - 3072) * 2048 + tid * 8;
    #pragma unroll
    for (int e = 0; e < 8; ++e) {
      const int j = base + e;
      bias_i[j] = bias[(j & 3) * kH + (j >> 2)];
    }
    return;
  }

  __shared__ unsigned short tile[8192];

  const bool isW = (b >= 2048);
  const int tileid = isW ? (b - 2048) : b;
  const int kt  = tileid & 31;
  const int blk = tileid >> 5;          // bm or hb

  const int r    = tid >> 1;            // dest row within tile 0..127
  const int half = tid & 1;             // kb
  const int k0   = kt * 64 + half * 32;

  const float* src;
  if (!isW) {
    const int row = blk * 128 + r;
    src = (k0 < kH) ? (old_h + (long)row * kH + k0)
                    : (input + (long)row * kH + (k0 - kH));
  } else {
    const int j = blk * 128 + r;
    const int g = j & 3, h = j >> 2;
    src = weights + ((long)g * kH + h) * kK + k0;
  }

  float4 v[8];
  const float4* s4 = (const float4*)src;
  #pragma unroll
  for (int q = 0; q < 8; ++q) v[q] = s4[q];   // 128B contiguous per lane

  const int mb = r >> 4, r15 = r & 15;
  #pragma unroll
  for (int lh = 0; lh < 4; ++lh) {
    const int dst = mb * 1024 + half * 512 + (lh * 16 + r15) * 8;
    *(u16x8*)&tile[dst] = pack8(v[2 * lh], v[2 * lh + 1]);
  }
  __syncthreads();

  unsigned short* out = (isW ? Ww : Aw) + (long)tileid * 8192;
  #pragma unroll
  for (int q = 0; q < 4; ++q)   // linear 16KB burst, fully coalesced
    *(u16x8*)(out + q * 2048 + tid * 8) = *(const u16x8*)&tile[q * 2048 + tid * 8];
}

// ---------------- Pass 2: bf16 MFMA GEMM, 2-phase double-buffer + fused epilogue ----------------
// Block: 128 batch rows x 128 gate cols (32 hidden x 4 interleaved gates).
// 4 waves (2x2 of 64x64). BK=64. dbuf LDS (64KB), global_load_lds width-16.
// Fragment-order tiles -> all ds_read_b128 sequential (conflict-free).
__global__ __launch_bounds__(256, 2) void sublstm_gemm(
    const unsigned short* __restrict__ Aw, const unsigned short* __restrict__ Ww,
    const float* __restrict__ bias_i, const float* __restrict__ old_cell,
    float* __restrict__ out) {

  __shared__ union SM {
    struct { unsigned short A0[8192]; unsigned short B0[8192];
             unsigned short A1[8192]; unsigned short B1[8192]; } t;  // 64 KB
    float Gc[32][132];                                               // epilogue overlay (in A0/B0)
  } sm;
  __shared__ float bias_s[128];

  const int tid  = threadIdx.x;
  const int lane = tid & 63;
  const int wid  = tid >> 6;
  const int wr   = wid >> 1;
  const int wc   = wid & 1;

  // XCD swizzle: per XCD, 64 consecutive blocks share one hb (W panel L2-resident)
  const int bid = blockIdx.x;
  const int swz = (bid & 7) * 256 + (bid >> 3);
  const int bm  = swz & 63;
  const int hb  = swz >> 6;

  if (tid < 128) bias_s[tid] = bias_i[hb * 128 + tid];

  const unsigned short* atile = Aw + ((long)bm * 32) * 8192;
  const unsigned short* btile = Ww + ((long)hb * 32) * 8192;
  const int soff = tid * 8;

  unsigned short* A0 = sm.t.A0; unsigned short* B0 = sm.t.B0;
  unsigned short* A1 = sm.t.A1; unsigned short* B1 = sm.t.B1;

  f32x4 acc[4][4];
  #pragma unroll
  for (int m = 0; m < 4; ++m)
    #pragma unroll
    for (int n = 0; n < 4; ++n)
      acc[m][n] = f32x4{0.f, 0.f, 0.f, 0.f};

#define STAGE(LA, LB, KT) do {                                                     \
    const unsigned short* asrc_ = atile + (long)(KT) * 8192 + soff;                \
    const unsigned short* bsrc_ = btile + (long)(KT) * 8192 + soff;                \
    _Pragma("unroll")                                                              \
    for (int i_ = 0; i_ < 4; ++i_) {                                               \
      __builtin_amdgcn_global_load_lds(                                            \
          (const __attribute__((address_space(1))) unsigned int*)(asrc_ + i_ * 2048), \
          (__attribute__((address_space(3))) unsigned int*)((LA) + i_ * 2048 + wid * 512), \
          16, 0, 0);                                                               \
      __builtin_amdgcn_global_load_lds(                                            \
          (const __attribute__((address_space(1))) unsigned int*)(bsrc_ + i_ * 2048), \
          (__attribute__((address_space(3))) unsigned int*)((LB) + i_ * 2048 + wid * 512), \
          16, 0, 0);                                                               \
    }                                                                              \
  } while (0)

#define COMPUTE(LA, LB) do {                                                       \
    _Pragma("unroll")                                                              \
    for (int kk_ = 0; kk_ < 2; ++kk_) {                                            \
      u16x8 af_[4], bf_[4];                                                        \
      _Pragma("unroll")                                                            \
      for (int m_ = 0; m_ < 4; ++m_)                                               \
        af_[m_] = *(const u16x8*)&(LA)[((wr * 4 + m_) * 2 + kk_) * 512 + lane * 8];\
      _Pragma("unroll")                                                            \
      for (int n_ = 0; n_ < 4; ++n_)                                               \
        bf_[n_] = *(const u16x8*)&(LB)[((wc * 4 + n_) * 2 + kk_) * 512 + lane * 8];\
      _Pragma("unroll")                                                            \
      for (int m_ = 0; m_ < 4; ++m_)                                               \
        _Pragma("unroll")                                                          \
        for (int n_ = 0; n_ < 4; ++n_)                                             \
          asm("v_mfma_f32_16x16x32_bf16 %0, %1, %2, %0"                            \
              : "+v"(acc[m_][n_]) : "v"(af_[m_]), "v"(bf_[n_]));                   \
    }                                                                              \
  } while (0)

  // prologue
  STAGE(A0, B0, 0);
  __syncthreads();   // compiler drains vmcnt(0)

  // 2-phase steady state: stage next buffer, compute current, barrier
  for (int kt = 0; kt + 2 < 32; kt += 2) {
    STAGE(A1, B1, kt + 1);
    COMPUTE(A0, B0);
    __syncthreads();
    STAGE(A0, B0, kt + 2);
    COMPUTE(A1, B1);
    __syncthreads();
  }
  // tail: b0 holds tile 30
  STAGE(A1, B1, 31);

  // prefetch old_cell under the final MFMA phases (retires with the tail barrier)
  float ocp[4][4];
  #pragma unroll
  for (int m = 0; m < 4; ++m)
    #pragma unroll
    for (int q = 0; q < 4; ++q) {
      const int r = (tid >> 5) + q * 8;
      const int grow = bm * 128 + (r >> 4) * 64 + m * 16 + (r & 15);
      ocp[m][q] = old_cell[(long)grow * kH + hb * 32 + (tid & 31)];
    }

  COMPUTE(A0, B0);
  __syncthreads();
  COMPUTE(A1, B1);

#undef STAGE
#undef COMPUTE

  // ---- fused epilogue: 4 row-chunks of 32 rows x 128 gate cols ----
  float* out_h = out;
  float* out_c = out + (long)kB * kH;

  #pragma unroll
  for (int m = 0; m < 4; ++m) {
    __syncthreads();  // previous chunk consumed / final MFMA reads done
    #pragma unroll
    for (int n = 0; n < 4; ++n) {
      const int col = wc * 64 + n * 16 + (lane & 15);  // C/D: col = lane&15
      #pragma unroll
      for (int j = 0; j < 4; ++j)
        sm.Gc[wr * 16 + (lane >> 4) * 4 + j][col] = acc[m][n][j];  // row=(lane>>4)*4+j
    }
    __syncthreads();

    #pragma unroll
    for (int q = 0; q < 4; ++q) {
      const int r = (tid >> 5) + q * 8;   // chunk row 0..31
      const int h = tid & 31;             // local hidden 0..31
      const float4 gv = *(const float4*)&sm.Gc[r][h * 4];  // i,o,z,f interleaved
      const float4 bv = *(const float4*)&bias_s[h * 4];
      const float gi = sigmoidf_(gv.x + bv.x);
      const float go = sigmoidf_(gv.y + bv.y);
      const float gz = sigmoidf_(gv.z + bv.z);
      const float gf = sigmoidf_(gv.w + bv.w);
      const int grow = bm * 128 + (r >> 4) * 64 + m * 16 + (r & 15);
      const long off = (long)grow * kH + hb * 32 + h;
      const float nc = ocp[m][q] * gf + gz - gi;
      out_h[off] = sigmoidf_(nc) - go;
      out_c[off] = nc;
    }
  }
}

// ---------------- Fallback (round-1 fused kernel) if ws too small ----------------
constexpr int FBM = 128, FBH = 32, FBN = 128, FBK = 32, FNKT = kK / FBK;

__global__ __launch_bounds__(256, 2) void sublstm_fused(
    const float* __restrict__ input, const float* __restrict__ weights,
    const float* __restrict__ bias, const float* __restrict__ old_h,
    const float* __restrict__ old_cell, float* __restrict__ out) {
  __shared__ unsigned short As[FBM][FBK + 8];
  __shared__ unsigned short Bs[FBN][FBK + 8];
  __shared__ float Gc[32][FBN + 4];

  const int tid = threadIdx.x, lane = tid & 63, wid = tid >> 6;
  const int wr = wid >> 1, wc = wid & 1;
  const int bid = blockIdx.x;
  const int bm = bid & 63, hh0 = (bid >> 6) * FBH;

  const int ra = tid >> 1, ca = (tid & 1) << 4;
  const long arow = (long)bm * FBM + ra;
  const int wrow = (ra >> 5) * kH + hh0 + (ra & 31);
  const float* abase_h = old_h + arow * kH + ca;
  const float* abase_x = input + arow * kH + ca - kH;
  const float* wbase = weights + (long)wrow * kK + ca;

  const int fr = lane & 15, ks = (lane >> 4) << 3;
  f32x4 acc[4][4];
  #pragma unroll
  for (int m = 0; m < 4; ++m)
    #pragma unroll
    for (int n = 0; n < 4; ++n) acc[m][n] = f32x4{0.f, 0.f, 0.f, 0.f};

  float4 a0, a1, a2, a3, b0, b1, b2, b3;
  {
    const float4* ap4 = (const float4*)abase_h;
    const float4* wp4 = (const float4*)wbase;
    a0 = ap4[0]; a1 = ap4[1]; a2 = ap4[2]; a3 = ap4[3];
    b0 = wp4[0]; b1 = wp4[1]; b2 = wp4[2]; b3 = wp4[3];
  }
  for (int kt = 0; kt < FNKT; ++kt) {
    u16x8 pa0 = pack8(a0, a1), pa1 = pack8(a2, a3);
    u16x8 pb0 = pack8(b0, b1), pb1 = pack8(b2, b3);
    __syncthreads();
    *(u16x8*)&As[ra][ca] = pa0; *(u16x8*)&As[ra][ca + 8] = pa1;
    *(u16x8*)&Bs[ra][ca] = pb0; *(u16x8*)&Bs[ra][ca + 8] = pb1;
    __syncthreads();
    if (kt + 1 < FNKT) {
      const int k0n = (kt + 1) * FBK;
      const float* ap = (k0n < kH) ? (abase_h + k0n) : (abase_x + k0n);
      const float4* ap4 = (const float4*)ap;
      const float4* wp4 = (const float4*)(wbase + k0n);
      a0 = ap4[0]; a1 = ap4[1]; a2 = ap4[2]; a3 = ap4[3];
      b0 = wp4[0]; b1 = wp4[1]; b2 = wp4[2]; b3 = wp4[3];
    }
    u16x8 af[4], bfv[4];
    #pragma unroll
    for (int m = 0; m < 4; ++m) af[m] = *(const u16x8*)&As[wr * 64 + m * 16 + fr][ks];
    #pragma unroll
    for (int n = 0; n < 4; ++n) bfv[n] = *(const u16x8*)&Bs[wc * 64 + n * 16 + fr][ks];
    #pragma unroll
    for (int m = 0; m < 4; ++m)
      #pragma unroll
      for (int n = 0; n < 4; ++n)
        asm("v_mfma_f32_16x16x32_bf16 %0, %1, %2, %0"
            : "+v"(acc[m][n]) : "v"(af[m]), "v"(bfv[n]));
  }
  float* out_h = out;
  float* out_c = out + (long)kB * kH;
  #pragma unroll
  for (int m = 0; m < 4; ++m) {
    __syncthreads();
    #pragma unroll
    for (int n = 0; n < 4; ++n) {
      const int col = wc * 64 + n * 16 + fr;
      #pragma unroll
      for (int j = 0; j < 4; ++j)
        Gc[wr * 16 + (lane >> 4) * 4 + j][col] = acc[m][n][j];
    }
    __syncthreads();
    #pragma unroll
    for (int q = 0; q < 4; ++q) {
      const int idx = tid + (q << 8);
      const int r = idx >> 5, h = idx & 31;
      const int hg = hh0 + h;
      const float gi = sigmoidf_(Gc[r][h] + bias[hg]);
      const float go = sigmoidf_(Gc[r][32 + h] + bias[kH + hg]);
      const float gz = sigmoidf_(Gc[r][64 + h] + bias[2 * kH + hg]);
      const float gf = sigmoidf_(Gc[r][96 + h] + bias[3 * kH + hg]);
      const int grow = bm * FBM + (r >> 4) * 64 + m * 16 + (r & 15);
      const long off = (long)grow * kH + hg;
      const float oc = old_cell[off];
      const float nc = oc * gf + gz - gi;
      out_h[off] = sigmoidf_(nc) - go;
      out_c[off] = nc;
    }
  }
}

}  // namespace

extern "C" void kernel_launch(void* const* d_in, const int* in_sizes, int n_in,
                              void* d_out, int out_size, void* d_ws, size_t ws_size,
                              hipStream_t stream) {
  const float* input    = (const float*)d_in[0];
  const float* weights  = (const float*)d_in[1];
  const float* bias     = (const float*)d_in[2];
  const float* old_h    = (const float*)d_in[3];
  const float* old_cell = (const float*)d_in[4];
  float* out = (float*)d_out;

  const size_t needA = (size_t)kB * kK * 2;      // 32 MB
  const size_t needW = (size_t)kG * kK * 2;      // 16 MB
  const size_t needBias = (size_t)kG * 4;        // 16 KB

  if (ws_size >= needA + needW + needBias) {
    unsigned short* Aw = (unsigned short*)d_ws;
    unsigned short* Ww = (unsigned short*)((char*)d_ws + needA);
    float* bias_i = (float*)((char*)d_ws + needA + needW);
    prep_pack<<<dim3(3074), dim3(256), 0, stream>>>(input, weights, bias, old_h,
                                                    Aw, Ww, bias_i);
    sublstm_gemm<<<dim3(2048), dim3(256), 0, stream>>>(Aw, Ww, bias_i, old_cell, out);
  } else {
    sublstm_fused<<<dim3(2048), dim3(256), 0, stream>>>(input, weights, bias, old_h,
                                                        old_cell, out);
  }
}

// Round 6
// 317.134 us; speedup vs baseline: 3.4127x; 1.0582x over previous
//
#include <hip/hip_runtime.h>
#include <hip/hip_bf16.h>

namespace {

constexpr int kB = 8192;   // batch
constexpr int kH = 1024;   // hidden
constexpr int kK = 2048;   // H + I
constexpr int kG = 4 * kH; // 4096 gate cols

typedef float f32x4 __attribute__((ext_vector_type(4)));
typedef unsigned short u16x8 __attribute__((ext_vector_type(8)));
typedef unsigned short u16x4 __attribute__((ext_vector_type(4)));

__device__ __forceinline__ unsigned short f2bf(float f) {
  return __builtin_bit_cast(unsigned short, __float2bfloat16(f));
}
__device__ __forceinline__ float sigmoidf_(float x) {
  return 1.0f / (1.0f + __expf(-x));
}
__device__ __forceinline__ u16x4 pack4(const float4 v) {
  return u16x4{f2bf(v.x), f2bf(v.y), f2bf(v.z), f2bf(v.w)};
}

// ---------------- Pass 1 (v3): coalesced pack f32 -> bf16 fragment-order tiles ----
// Packed tile (8192 shorts = 128 rows x 64 k):
//   off = mb*1024 + kb*512 + lh*128 + r15*8 + e  <->  row = mb*16+r15, k = kb*32+lh*8+e
// A tiles: Aw[(rb*32 + kt)*8192], rb = row/128 (0..63), kt = k/64 (0..31)
// W tiles: Ww[(wb*32 + kt)*8192], wb = gatecol j/128 (0..31); j = h*4+g <- weights row g*1024+h
// One block packs 128 rows x 256 k (4 tiles). Reads: per-instr 64 lanes x 16B
// contiguous (1KB). LDS row-major [128][280] shorts (pad spreads banks on the
// fragment-gather read-back). Writes: linear 1KB bursts.
__global__ __launch_bounds__(256) void prep_pack(
    const float* __restrict__ input, const float* __restrict__ weights,
    const float* __restrict__ bias, const float* __restrict__ old_h,
    unsigned short* __restrict__ Aw, unsigned short* __restrict__ Ww,
    float* __restrict__ bias_i) {
  const int b = blockIdx.x;
  const int tid = threadIdx.x;

  if (b >= 768) {  // bias interleave: 2 blocks x 256 threads x 8
    const int base = (b - 768) * 2048 + tid * 8;
    #pragma unroll
    for (int e = 0; e < 8; ++e) {
      const int j = base + e;
      bias_i[j] = bias[(j & 3) * kH + (j >> 2)];
    }
    return;
  }

  __shared__ unsigned short lbuf[128 * 280];  // 70 KB, row stride 280 shorts

  const int wid = tid >> 6, lane = tid & 63;
  const bool isW = (b >= 512);
  const int blk = isW ? (b - 512) : b;
  const int rb = blk >> 3;    // row-block: A 0..63, W 0..31
  const int kc = blk & 7;     // 256-col chunk

  // ---- read + convert (rows it*4 + wid, 64 float4 per row across lanes) ----
  #pragma unroll
  for (int io = 0; io < 4; ++io) {
    float4 v[8];
    #pragma unroll
    for (int ii = 0; ii < 8; ++ii) {
      const int row = (io * 8 + ii) * 4 + wid;
      const float* base;
      if (!isW) {
        const long rowg = (long)rb * 128 + row;
        base = (kc < 4) ? (old_h + rowg * kH + kc * 256)
                        : (input + rowg * kH + (kc * 256 - kH));
      } else {
        const int j = rb * 128 + row;
        const int g = j & 3, h = j >> 2;
        base = weights + ((long)g * kH + h) * kK + kc * 256;
      }
      v[ii] = ((const float4*)base)[lane];
    }
    #pragma unroll
    for (int ii = 0; ii < 8; ++ii) {
      const int row = (io * 8 + ii) * 4 + wid;
      *(u16x4*)&lbuf[row * 280 + lane * 4] = pack4(v[ii]);
    }
  }
  __syncthreads();

  // ---- fragment-order gather + linear burst out (4 tiles x 16KB) ----
  unsigned short* dst = (isW ? Ww : Aw) + ((long)rb * 32 + kc * 4) * 8192;
  #pragma unroll
  for (int it = 0; it < 16; ++it) {
    const int o = (it * 256 + tid) * 8;       // 0..32760
    const int oo = o & 8191;
    const int tl = o >> 13;
    const int r15 = (oo >> 3) & 15;
    const int lh = (oo >> 7) & 3;
    const int kb = (oo >> 9) & 1;
    const int mb = oo >> 10;
    const int row = mb * 16 + r15;
    const int cs = tl * 64 + kb * 32 + lh * 8;
    *(u16x8*)(dst + o) = *(const u16x8*)&lbuf[row * 280 + cs];
  }
}

// ---------------- Pass 2: 256x256 bf16 MFMA GEMM, 2-phase dbuf + fused epilogue ----
// Block: 256 batch rows x 256 gate cols (64 hidden x 4 gates). 8 waves (2Mx4N),
// per-wave 128x64 = acc[8][4]. BK=64. LDS 128KB dbuf, global_load_lds width-16,
// fragment-order tiles -> all ds_read_b128 lane-linear (conflict-free).
__global__ __launch_bounds__(512, 2) void sublstm_gemm(
    const unsigned short* __restrict__ Aw, const unsigned short* __restrict__ Ww,
    const float* __restrict__ bias_i, const float* __restrict__ old_cell,
    float* __restrict__ out) {

  __shared__ union SM {
    struct { unsigned short A0[16384]; unsigned short B0[16384];
             unsigned short A1[16384]; unsigned short B1[16384]; } t;  // 128 KB
    float Gc[32][260];                                                 // epilogue overlay
  } sm;
  __shared__ float bias_s[256];

  const int tid  = threadIdx.x;
  const int lane = tid & 63;
  const int wid  = tid >> 6;
  const int wr   = wid >> 2;   // 0..1 (row half, 128 rows)
  const int wc   = wid & 3;    // 0..3 (64-col slice)

  // XCD swizzle: per-XCD walk in {2 A-panels + 2 W-panels} = 4MB L2 working set
  const int bid = blockIdx.x;                 // 0..511
  const int swz = (bid & 7) * 64 + (bid >> 3);
  const int xc  = swz >> 6;                   // 0..7
  const int i6  = swz & 63;
  const int bm  = (i6 >> 2) * 2 + (i6 & 1);   // 0..31
  const int hb  = xc * 2 + ((i6 >> 1) & 1);   // 0..15

  if (tid < 256) bias_s[tid] = bias_i[hb * 256 + tid];

  unsigned short* A0 = sm.t.A0; unsigned short* B0 = sm.t.B0;
  unsigned short* A1 = sm.t.A1; unsigned short* B1 = sm.t.B1;

  f32x4 acc[8][4];
  #pragma unroll
  for (int m = 0; m < 8; ++m)
    #pragma unroll
    for (int n = 0; n < 4; ++n)
      acc[m][n] = f32x4{0.f, 0.f, 0.f, 0.f};

#define STAGE(LA, LB, KT) do {                                                     \
    _Pragma("unroll")                                                              \
    for (int i_ = 0; i_ < 4; ++i_) {                                               \
      __builtin_amdgcn_global_load_lds(                                            \
          (const __attribute__((address_space(1))) unsigned int*)(                 \
              Aw + ((long)((2 * bm + (i_ >> 1)) * 32 + (KT))) * 8192               \
                 + (i_ & 1) * 4096 + tid * 8),                                     \
          (__attribute__((address_space(3))) unsigned int*)((LA) + i_ * 4096 + tid * 8), \
          16, 0, 0);                                                               \
      __builtin_amdgcn_global_load_lds(                                            \
          (const __attribute__((address_space(1))) unsigned int*)(                 \
              Ww + ((long)((2 * hb + (i_ >> 1)) * 32 + (KT))) * 8192               \
                 + (i_ & 1) * 4096 + tid * 8),                                     \
          (__attribute__((address_space(3))) unsigned int*)((LB) + i_ * 4096 + tid * 8), \
          16, 0, 0);                                                               \
    }                                                                              \
  } while (0)

#define COMPUTE(LA, LB) do {                                                       \
    _Pragma("unroll")                                                              \
    for (int kk_ = 0; kk_ < 2; ++kk_) {                                            \
      u16x8 bf_[4];                                                                \
      _Pragma("unroll")                                                            \
      for (int n_ = 0; n_ < 4; ++n_)                                               \
        bf_[n_] = *(const u16x8*)&(LB)[(wc >> 1) * 8192 + ((wc & 1) * 4 + n_) * 1024 \
                                        + kk_ * 512 + lane * 8];                   \
      _Pragma("unroll")                                                            \
      for (int m_ = 0; m_ < 8; ++m_) {                                             \
        u16x8 af_ = *(const u16x8*)&(LA)[wr * 8192 + m_ * 1024 + kk_ * 512 + lane * 8]; \
        _Pragma("unroll")                                                          \
        for (int n_ = 0; n_ < 4; ++n_)                                             \
          asm("v_mfma_f32_16x16x32_bf16 %0, %1, %2, %0"                            \
              : "+v"(acc[m_][n_]) : "v"(af_), "v"(bf_[n_]));                       \
      }                                                                            \
    }                                                                              \
  } while (0)

  // prologue
  STAGE(A0, B0, 0);
  __syncthreads();

  for (int kt = 0; kt + 2 < 32; kt += 2) {
    STAGE(A1, B1, kt + 1);
    COMPUTE(A0, B0);
    __syncthreads();
    STAGE(A0, B0, kt + 2);
    COMPUTE(A1, B1);
    __syncthreads();
  }
  STAGE(A1, B1, 31);

  // prefetch epilogue chunk 0's old_cell under the last MFMA phases
  float cnx[4];
  #pragma unroll
  for (int q = 0; q < 4; ++q) {
    const int grow = bm * 256 + q * 8 + wid;
    cnx[q] = old_cell[(long)grow * kH + hb * 64 + lane];
  }

  COMPUTE(A0, B0);
  __syncthreads();
  COMPUTE(A1, B1);

#undef STAGE
#undef COMPUTE

  // ---- fused epilogue: 8 chunks of 32 rows x 256 gate cols ----
  float* out_h = out;
  float* out_c = out + (long)kB * kH;

  #pragma unroll
  for (int c = 0; c < 8; ++c) {
    const int wrc = c >> 2, mm = c & 3;
    __syncthreads();  // previous chunk consumed / K-loop ds_reads retired
    if (wr == wrc) {
      #pragma unroll
      for (int m2 = 0; m2 < 2; ++m2)
        #pragma unroll
        for (int n = 0; n < 4; ++n) {
          const int col = wc * 64 + n * 16 + (lane & 15);   // C/D col = lane&15
          const int rb_ = m2 * 16 + (lane >> 4) * 4;        // row=(lane>>4)*4+j
          #pragma unroll
          for (int j = 0; j < 4; ++j)
            sm.Gc[rb_ + j][col] = acc[mm * 2 + m2][n][j];
        }
    }
    __syncthreads();

    float cc[4];
    #pragma unroll
    for (int q = 0; q < 4; ++q) cc[q] = cnx[q];
    if (c < 7) {  // prefetch next chunk's cells
      const int c2 = c + 1;
      #pragma unroll
      for (int q = 0; q < 4; ++q) {
        const int grow = bm * 256 + (c2 >> 2) * 128 + (c2 & 3) * 32 + q * 8 + wid;
        cnx[q] = old_cell[(long)grow * kH + hb * 64 + lane];
      }
    }

    #pragma unroll
    for (int q = 0; q < 4; ++q) {
      const int r = q * 8 + wid;            // chunk row 0..31
      const float4 gv = *(const float4*)&sm.Gc[r][lane * 4];  // i,o,z,f
      const float4 bv = *(const float4*)&bias_s[lane * 4];
      const float gi = sigmoidf_(gv.x + bv.x);
      const float go = sigmoidf_(gv.y + bv.y);
      const float gz = sigmoidf_(gv.z + bv.z);
      const float gf = sigmoidf_(gv.w + bv.w);
      const int grow = bm * 256 + wrc * 128 + mm * 32 + r;
      const long off = (long)grow * kH + hb * 64 + lane;
      const float nc = cc[q] * gf + gz - gi;
      out_h[off] = sigmoidf_(nc) - go;
      out_c[off] = nc;
    }
  }
}

// ---------------- Fallback (round-1 fused kernel) if ws too small ----------------
constexpr int FBM = 128, FBH = 32, FBN = 128, FBK = 32, FNKT = kK / FBK;

__device__ __forceinline__ u16x8 pack8f(const float4 v0, const float4 v1) {
  return u16x8{f2bf(v0.x), f2bf(v0.y), f2bf(v0.z), f2bf(v0.w),
               f2bf(v1.x), f2bf(v1.y), f2bf(v1.z), f2bf(v1.w)};
}

__global__ __launch_bounds__(256, 2) void sublstm_fused(
    const float* __restrict__ input, const float* __restrict__ weights,
    const float* __restrict__ bias, const float* __restrict__ old_h,
    const float* __restrict__ old_cell, float* __restrict__ out) {
  __shared__ unsigned short As[FBM][FBK + 8];
  __shared__ unsigned short Bs[FBN][FBK + 8];
  __shared__ float Gc[32][FBN + 4];

  const int tid = threadIdx.x, lane = tid & 63, wid = tid >> 6;
  const int wr = wid >> 1, wc = wid & 1;
  const int bid = blockIdx.x;
  const int bm = bid & 63, hh0 = (bid >> 6) * FBH;

  const int ra = tid >> 1, ca = (tid & 1) << 4;
  const long arow = (long)bm * FBM + ra;
  const int wrow = (ra >> 5) * kH + hh0 + (ra & 31);
  const float* abase_h = old_h + arow * kH + ca;
  const float* abase_x = input + arow * kH + ca - kH;
  const float* wbase = weights + (long)wrow * kK + ca;

  const int fr = lane & 15, ks = (lane >> 4) << 3;
  f32x4 acc[4][4];
  #pragma unroll
  for (int m = 0; m < 4; ++m)
    #pragma unroll
    for (int n = 0; n < 4; ++n) acc[m][n] = f32x4{0.f, 0.f, 0.f, 0.f};

  float4 a0, a1, a2, a3, b0, b1, b2, b3;
  {
    const float4* ap4 = (const float4*)abase_h;
    const float4* wp4 = (const float4*)wbase;
    a0 = ap4[0]; a1 = ap4[1]; a2 = ap4[2]; a3 = ap4[3];
    b0 = wp4[0]; b1 = wp4[1]; b2 = wp4[2]; b3 = wp4[3];
  }
  for (int kt = 0; kt < FNKT; ++kt) {
    u16x8 pa0 = pack8f(a0, a1), pa1 = pack8f(a2, a3);
    u16x8 pb0 = pack8f(b0, b1), pb1 = pack8f(b2, b3);
    __syncthreads();
    *(u16x8*)&As[ra][ca] = pa0; *(u16x8*)&As[ra][ca + 8] = pa1;
    *(u16x8*)&Bs[ra][ca] = pb0; *(u16x8*)&Bs[ra][ca + 8] = pb1;
    __syncthreads();
    if (kt + 1 < FNKT) {
      const int k0n = (kt + 1) * FBK;
      const float* ap = (k0n < kH) ? (abase_h + k0n) : (abase_x + k0n);
      const float4* ap4 = (const float4*)ap;
      const float4* wp4 = (const float4*)(wbase + k0n);
      a0 = ap4[0]; a1 = ap4[1]; a2 = ap4[2]; a3 = ap4[3];
      b0 = wp4[0]; b1 = wp4[1]; b2 = wp4[2]; b3 = wp4[3];
    }
    u16x8 af[4], bfv[4];
    #pragma unroll
    for (int m = 0; m < 4; ++m) af[m] = *(const u16x8*)&As[wr * 64 + m * 16 + fr][ks];
    #pragma unroll
    for (int n = 0; n < 4; ++n) bfv[n] = *(const u16x8*)&Bs[wc * 64 + n * 16 + fr][ks];
    #pragma unroll
    for (int m = 0; m < 4; ++m)
      #pragma unroll
      for (int n = 0; n < 4; ++n)
        asm("v_mfma_f32_16x16x32_bf16 %0, %1, %2, %0"
            : "+v"(acc[m][n]) : "v"(af[m]), "v"(bfv[n]));
  }
  float* out_h = out;
  float* out_c = out + (long)kB * kH;
  #pragma unroll
  for (int m = 0; m < 4; ++m) {
    __syncthreads();
    #pragma unroll
    for (int n = 0; n < 4; ++n) {
      const int col = wc * 64 + n * 16 + fr;
      #pragma unroll
      for (int j = 0; j < 4; ++j)
        Gc[wr * 16 + (lane >> 4) * 4 + j][col] = acc[m][n][j];
    }
    __syncthreads();
    #pragma unroll
    for (int q = 0; q < 4; ++q) {
      const int idx = tid + (q << 8);
      const int r = idx >> 5, h = idx & 31;
      const int hg = hh0 + h;
      const float gi = sigmoidf_(Gc[r][h] + bias[hg]);
      const float go = sigmoidf_(Gc[r][32 + h] + bias[kH + hg]);
      const float gz = sigmoidf_(Gc[r][64 + h] + bias[2 * kH + hg]);
      const float gf = sigmoidf_(Gc[r][96 + h] + bias[3 * kH + hg]);
      const int grow = bm * FBM + (r >> 4) * 64 + m * 16 + (r & 15);
      const long off = (long)grow * kH + hg;
      const float oc = old_cell[off];
      const float nc = oc * gf + gz - gi;
      out_h[off] = sigmoidf_(nc) - go;
      out_c[off] = nc;
    }
  }
}

}  // namespace

extern "C" void kernel_launch(void* const* d_in, const int* in_sizes, int n_in,
                              void* d_out, int out_size, void* d_ws, size_t ws_size,
                              hipStream_t stream) {
  const float* input    = (const float*)d_in[0];
  const float* weights  = (const float*)d_in[1];
  const float* bias     = (const float*)d_in[2];
  const float* old_h    = (const float*)d_in[3];
  const float* old_cell = (const float*)d_in[4];
  float* out = (float*)d_out;

  const size_t needA = (size_t)kB * kK * 2;      // 32 MB
  const size_t needW = (size_t)kG * kK * 2;      // 16 MB
  const size_t needBias = (size_t)kG * 4;        // 16 KB

  if (ws_size >= needA + needW + needBias) {
    unsigned short* Aw = (unsigned short*)d_ws;
    unsigned short* Ww = (unsigned short*)((char*)d_ws + needA);
    float* bias_i = (float*)((char*)d_ws + needA + needW);
    prep_pack<<<dim3(770), dim3(256), 0, stream>>>(input, weights, bias, old_h,
                                                   Aw, Ww, bias_i);
    sublstm_gemm<<<dim3(512), dim3(512), 0, stream>>>(Aw, Ww, bias_i, old_cell, out);
  } else {
    sublstm_fused<<<dim3(2048), dim3(256), 0, stream>>>(input, weights, bias, old_h,
                                                        old_cell, out);
  }
}